// Round 1
// baseline (2037.518 us; speedup 1.0000x reference)
//
#include <hip/hip_runtime.h>
#include <math.h>

#define DM 512
#define HH 8
#define DK 64
#define NSEQ 512

typedef unsigned char u8;
typedef unsigned int u32;

// ---------------- mask normalization (dtype-sniffing) ----------------
// Masks come from jnp bool arrays; harness may deliver them as 1-byte bools
// or int32. Detect: viewed as u32 words, packed bools produce words > 1.
__global__ __launch_bounds__(256) void norm_mask_kernel(const u32* __restrict__ m,
                                                        u8* __restrict__ o, int nElem) {
  __shared__ int flag;
  if (threadIdx.x == 0) flag = 0;
  __syncthreads();
  const int nw = nElem >> 2;  // safe to read for both dtypes
  int local = 0;
  for (int i = threadIdx.x; i < nw; i += 256)
    if (m[i] > 1u) local = 1;
  if (local) atomicOr(&flag, 1);
  __syncthreads();
  const bool packed = (flag != 0);  // true -> 1-byte bools
  const u8* mb = (const u8*)m;
  for (int i = threadIdx.x; i < nElem; i += 256)
    o[i] = packed ? (mb[i] ? (u8)1 : (u8)0) : (u8)(m[i] != 0u);
}

// ---------------- fp32 tiled GEMM: C[M,512] = A[M,512] @ W[512,512] + bias ----
// mode 0: C[m][n] plain row-major write
// mode 1: scatter to [b, h, n_seq, d] layout (b = m>>9, n_seq = m&511,
//         h = n>>6, d = n&63). n-tile is 64 wide so h is uniform per block.
__global__ __launch_bounds__(256) void gemm512_kernel(
    const float* __restrict__ A, const float* __restrict__ W,
    const float* __restrict__ bias, float* __restrict__ C, const int mode) {
  __shared__ float As[16][68];  // [k][m], padded: conflict-free + 16B aligned
  __shared__ float Bs[16][64];  // [k][n]
  const int t = threadIdx.x;
  const int bid = blockIdx.x;
  const int m0 = (bid >> 3) << 6;
  const int n0 = (bid & 7) << 6;
  const int r = t >> 4, c = t & 15;
  float acc[4][4];
#pragma unroll
  for (int i = 0; i < 4; ++i)
#pragma unroll
    for (int j = 0; j < 4; ++j) acc[i][j] = 0.f;

  for (int kt = 0; kt < 32; ++kt) {
    const int k0 = kt << 4;
#pragma unroll
    for (int i = 0; i < 4; ++i) {
      const int idx = t + (i << 8);
      const int ar = idx >> 4, ak = idx & 15;
      As[ak][ar] = A[(long)(m0 + ar) * DM + k0 + ak];
    }
#pragma unroll
    for (int i = 0; i < 4; ++i) {
      const int br = (t >> 6) + (i << 2), bc = t & 63;
      Bs[br][bc] = W[(long)(k0 + br) * DM + n0 + bc];
    }
    __syncthreads();
#pragma unroll
    for (int kk = 0; kk < 16; ++kk) {
      const float4 a = *(const float4*)&As[kk][r << 2];
      const float4 bb = *(const float4*)&Bs[kk][c << 2];
      const float av[4] = {a.x, a.y, a.z, a.w};
      const float bw[4] = {bb.x, bb.y, bb.z, bb.w};
#pragma unroll
      for (int i = 0; i < 4; ++i)
#pragma unroll
        for (int j = 0; j < 4; ++j) acc[i][j] += av[i] * bw[j];
    }
    __syncthreads();
  }
  const float4 bv = *(const float4*)&bias[n0 + (c << 2)];
  const float bias4[4] = {bv.x, bv.y, bv.z, bv.w};
  if (mode == 0) {
#pragma unroll
    for (int i = 0; i < 4; ++i) {
      const int m = m0 + (r << 2) + i;
      float4 o;
      o.x = acc[i][0] + bias4[0];
      o.y = acc[i][1] + bias4[1];
      o.z = acc[i][2] + bias4[2];
      o.w = acc[i][3] + bias4[3];
      *(float4*)&C[(long)m * DM + n0 + (c << 2)] = o;
    }
  } else {
    const int h = n0 >> 6;
#pragma unroll
    for (int i = 0; i < 4; ++i) {
      const int m = m0 + (r << 2) + i;
      const int bi = m >> 9, n = m & (NSEQ - 1);
      float4 o;
      o.x = acc[i][0] + bias4[0];
      o.y = acc[i][1] + bias4[1];
      o.z = acc[i][2] + bias4[2];
      o.w = acc[i][3] + bias4[3];
      *(float4*)&C[(((long)bi * HH + h) * NSEQ + n) * DK + (c << 2)] = o;
    }
  }
}

// ---------------- fused dual attention ----------------
// One block = (b, h, 8 q-rows). Full score rows for both branches in LDS;
// softmax + cross-mixing in place; AV straight from global v.
__global__ __launch_bounds__(256) void attn_fused_kernel(
    const float* __restrict__ q, const float* __restrict__ k1,
    const float* __restrict__ k2, const float* __restrict__ v1,
    const float* __restrict__ v2, const float* __restrict__ aw,
    const u8* __restrict__ mR, const u8* __restrict__ mG,
    float* __restrict__ c1, float* __restrict__ c2) {
  __shared__ float q_s[8][68];
  __shared__ float ks[64][68];
  __shared__ float e1s[8][513];
  __shared__ float e2s[8][513];

  const int t = threadIdx.x;
  const int bid = blockIdx.x;
  const int qt = bid & 63;
  const int h = (bid >> 6) & 7;
  const int b = bid >> 9;
  const int q0 = qt << 3;
  const long bh = (long)b * HH + h;
  const long bh_base = bh * NSEQ * DK;

  {  // load Q tile [8][64]
    const int row = t >> 5;
    const int dd = (t & 31) << 1;
    *(float2*)&q_s[row][dd] =
        *(const float2*)&q[bh_base + (long)(q0 + row) * DK + dd];
  }
  __syncthreads();

  const int qi = t >> 5;  // row owned by this 32-lane group
  const int kk = t & 31;

  float4 qv[16];  // full q row in registers
#pragma unroll
  for (int i = 0; i < 16; ++i) qv[i] = *(const float4*)&q_s[qi][i << 2];

  const float scale = 0.125f;  // 1/sqrt(64)
  const float* awp = aw + (bh * NSEQ + q0) * NSEQ;
  const u8* mRp = mR + b * NSEQ;
  const u8* mGp = mG + b * NSEQ;

  for (int kt = 0; kt < NSEQ; kt += 64) {
    // ---- branch 1 (regions / K1) ----
    __syncthreads();
#pragma unroll
    for (int i = 0; i < 4; ++i) {
      const int idx = t + (i << 8);
      const int row = idx >> 4, dq = (idx & 15) << 2;
      *(float4*)&ks[row][dq] =
          *(const float4*)&k1[bh_base + (long)(kt + row) * DK + dq];
    }
    __syncthreads();
#pragma unroll
    for (int j = 0; j < 2; ++j) {
      const int k = kk + (j << 5);
      float d1 = 0.f;
#pragma unroll
      for (int i = 0; i < 16; ++i) {
        const float4 kv = *(const float4*)&ks[k][i << 2];
        const float4 qq = qv[i];
        d1 += qq.x * kv.x + qq.y * kv.y + qq.z * kv.z + qq.w * kv.w;
      }
      const float awv = awp[qi * NSEQ + kt + k];
      float s1 = d1 * scale * awv;
      if (mRp[kt + k]) s1 = -INFINITY;
      e1s[qi][kt + k] = s1;
    }
    // ---- branch 2 (grids / K2) ----
    __syncthreads();
#pragma unroll
    for (int i = 0; i < 4; ++i) {
      const int idx = t + (i << 8);
      const int row = idx >> 4, dq = (idx & 15) << 2;
      *(float4*)&ks[row][dq] =
          *(const float4*)&k2[bh_base + (long)(kt + row) * DK + dq];
    }
    __syncthreads();
#pragma unroll
    for (int j = 0; j < 2; ++j) {
      const int k = kk + (j << 5);
      float d2 = 0.f;
#pragma unroll
      for (int i = 0; i < 16; ++i) {
        const float4 kv = *(const float4*)&ks[k][i << 2];
        const float4 qq = qv[i];
        d2 += qq.x * kv.x + qq.y * kv.y + qq.z * kv.z + qq.w * kv.w;
      }
      const float awv = awp[qi * NSEQ + kt + k];
      float s2 = d2 * scale * awv;
      if (mGp[kt + k]) s2 = -INFINITY;
      e2s[qi][kt + k] = s2;
    }
  }
  __syncthreads();

  // ---- softmax per row (32 lanes own row qi) ----
  float m1 = -INFINITY, m2 = -INFINITY;
#pragma unroll
  for (int i = 0; i < 16; ++i) {
    m1 = fmaxf(m1, e1s[qi][kk + (i << 5)]);
    m2 = fmaxf(m2, e2s[qi][kk + (i << 5)]);
  }
#pragma unroll
  for (int o = 16; o > 0; o >>= 1) {
    m1 = fmaxf(m1, __shfl_xor(m1, o));
    m2 = fmaxf(m2, __shfl_xor(m2, o));
  }
  float e1v[16], e2v[16];
  float s1 = 0.f, s2 = 0.f;
#pragma unroll
  for (int i = 0; i < 16; ++i) {
    e1v[i] = __expf(e1s[qi][kk + (i << 5)] - m1);
    e2v[i] = __expf(e2s[qi][kk + (i << 5)] - m2);
    s1 += e1v[i];
    s2 += e2v[i];
  }
#pragma unroll
  for (int o = 16; o > 0; o >>= 1) {
    s1 += __shfl_xor(s1, o);
    s2 += __shfl_xor(s2, o);
  }
  const float inv1 = 1.f / s1, inv2 = 1.f / s2;
#pragma unroll
  for (int i = 0; i < 16; ++i) {
    const float p1 = e1v[i] * inv1;
    const float p2 = e2v[i] * inv2;
    e1s[qi][kk + (i << 5)] = p1 + 0.1f * p2;  // weights for V1
    e2s[qi][kk + (i << 5)] = p2 + 0.1f * p1;  // weights for V2
  }
  __syncthreads();

  // ---- AV: each lane owns 2 d-columns of row qi ----
  const int d0 = kk << 1;
  const float* v1p = v1 + bh_base + d0;
  const float* v2p = v2 + bh_base + d0;
  float a1x = 0.f, a1y = 0.f, a2x = 0.f, a2y = 0.f;
#pragma unroll 4
  for (int k = 0; k < NSEQ; ++k) {
    const float w1 = e1s[qi][k];
    const float w2 = e2s[qi][k];
    const float2 vv1 = *(const float2*)&v1p[(long)k * DK];
    const float2 vv2 = *(const float2*)&v2p[(long)k * DK];
    a1x += w1 * vv1.x;
    a1y += w1 * vv1.y;
    a2x += w2 * vv2.x;
    a2y += w2 * vv2.y;
  }
  const long off = ((long)b * NSEQ + q0 + qi) * DM + h * DK + d0;
  float2 r1;
  r1.x = a1x;
  r1.y = a1y;
  float2 r2;
  r2.x = a2x;
  r2.y = a2y;
  *(float2*)&c1[off] = r1;
  *(float2*)&c2[off] = r2;
}

extern "C" void kernel_launch(void* const* d_in, const int* in_sizes, int n_in,
                              void* d_out, int out_size, void* d_ws, size_t ws_size,
                              hipStream_t stream) {
  const float* regions = (const float*)d_in[0];
  const float* grids = (const float*)d_in[1];
  const float* interests = (const float*)d_in[2];
  const void* maskR_raw = d_in[3];
  const void* maskG_raw = d_in[4];
  const float* aw = (const float*)d_in[5];
  const float* Wq = (const float*)d_in[6];
  const float* bq = (const float*)d_in[7];
  const float* Wk = (const float*)d_in[8];
  const float* bk = (const float*)d_in[9];
  const float* Wv = (const float*)d_in[10];
  const float* bvv = (const float*)d_in[11];
  const float* Wo1 = (const float*)d_in[12];
  const float* bo1 = (const float*)d_in[13];
  const float* Wo2 = (const float*)d_in[14];
  const float* bo2 = (const float*)d_in[15];

  const int B = in_sizes[0] / (DM * NSEQ);  // 16
  const long per = (long)B * NSEQ * DM;     // elements per [b, nq, 512] tensor

  float* ws = (float*)d_ws;
  float* q_ws = ws;
  float* k1_ws = ws + per;
  float* k2_ws = ws + 2 * per;
  float* v1_ws = ws + 3 * per;
  float* v2_ws = ws + 4 * per;
  float* c1_ws = ws + 5 * per;
  float* c2_ws = ws + 6 * per;
  u8* mR = (u8*)(ws + 7 * per);
  u8* mG = mR + (long)B * NSEQ;

  float* out1 = (float*)d_out;
  float* out2 = out1 + per;

  const int nMask = B * NSEQ;
  norm_mask_kernel<<<1, 256, 0, stream>>>((const u32*)maskR_raw, mR, nMask);
  norm_mask_kernel<<<1, 256, 0, stream>>>((const u32*)maskG_raw, mG, nMask);

  const int gemmGrid = (B * NSEQ / 64) * (DM / 64);  // 1024
  gemm512_kernel<<<gemmGrid, 256, 0, stream>>>(interests, Wq, bq, q_ws, 1);
  gemm512_kernel<<<gemmGrid, 256, 0, stream>>>(regions, Wk, bk, k1_ws, 1);
  gemm512_kernel<<<gemmGrid, 256, 0, stream>>>(regions, Wv, bvv, v1_ws, 1);
  gemm512_kernel<<<gemmGrid, 256, 0, stream>>>(grids, Wk, bk, k2_ws, 1);
  gemm512_kernel<<<gemmGrid, 256, 0, stream>>>(grids, Wv, bvv, v2_ws, 1);

  attn_fused_kernel<<<B * HH * (NSEQ / 8), 256, 0, stream>>>(
      q_ws, k1_ws, k2_ws, v1_ws, v2_ws, aw, mR, mG, c1_ws, c2_ws);

  gemm512_kernel<<<gemmGrid, 256, 0, stream>>>(c1_ws, Wo1, bo1, out1, 0);
  gemm512_kernel<<<gemmGrid, 256, 0, stream>>>(c2_ws, Wo2, bo2, out2, 0);
}

// Round 4
// 851.591 us; speedup vs baseline: 2.3926x; 2.3926x over previous
//
#include <hip/hip_runtime.h>
#include <math.h>

#define DM 512
#define HH 8
#define DK 64
#define NSEQ 512

typedef unsigned char u8;
typedef unsigned int u32;
typedef unsigned short u16;
typedef __attribute__((ext_vector_type(8))) short bf16x8;
typedef __attribute__((ext_vector_type(4))) float f32x4;

#define MFMA16(a, b, c) __builtin_amdgcn_mfma_f32_16x16x32_bf16(a, b, c, 0, 0, 0)

__device__ __forceinline__ u32 f2bf(float f) {
  u32 u = __builtin_bit_cast(u32, f);
  return (u + 0x7fffu + ((u >> 16) & 1u)) >> 16;  // RNE
}
__device__ __forceinline__ u32 packbf(float a, float b) {
  return f2bf(a) | (f2bf(b) << 16);
}
__device__ __forceinline__ float bfr(float f) {  // round to bf16 grid
  return __builtin_bit_cast(float, f2bf(f) << 16);
}

// ---------------- mask normalization (dtype-sniffing) ----------------
__global__ __launch_bounds__(256) void norm_mask_kernel(const u32* __restrict__ m,
                                                        u8* __restrict__ o, int nElem) {
  __shared__ int flag;
  if (threadIdx.x == 0) flag = 0;
  __syncthreads();
  const int nw = nElem >> 2;
  int local = 0;
  for (int i = threadIdx.x; i < nw; i += 256)
    if (m[i] > 1u) local = 1;
  if (local) atomicOr(&flag, 1);
  __syncthreads();
  const bool packed = (flag != 0);  // 1-byte bools
  const u8* mb = (const u8*)m;
  for (int i = threadIdx.x; i < nElem; i += 256)
    o[i] = packed ? (mb[i] ? (u8)1 : (u8)0) : (u8)(m[i] != 0u);
}

// ---------------- fp32 tiled GEMM: C[M,512] = A[M,512] @ W[512,512] + bias ----
// mode 0: A row-major [m][512], fp32 C row-major
// mode 1: A row-major, bf16 scatter to [b, h, seq, 64]
// mode 2: A row-major, bf16 transposed scatter to [b, h, 64, seq]  (for V)
// mode 3: A in [b, h, q, 64] layout (m = b*512+q, k = h*64+d), fp32 C row-major
__global__ __launch_bounds__(256) void gemm512_kernel(
    const float* __restrict__ A, const float* __restrict__ W,
    const float* __restrict__ bias, void* __restrict__ C, const int mode) {
  __shared__ float As[16][68];
  __shared__ float Bs[16][64];
  const int t = threadIdx.x;
  const int bid = blockIdx.x;
  const int m0 = (bid >> 3) << 6;
  const int n0 = (bid & 7) << 6;
  const int r = t >> 4, c = t & 15;
  float acc[4][4];
#pragma unroll
  for (int i = 0; i < 4; ++i)
#pragma unroll
    for (int j = 0; j < 4; ++j) acc[i][j] = 0.f;

  for (int kt = 0; kt < 32; ++kt) {
    const int k0 = kt << 4;
    if (mode == 3) {
#pragma unroll
      for (int i = 0; i < 4; ++i) {
        const int idx = t + (i << 8);
        const int ar = idx >> 4, ak = idx & 15;
        const int m = m0 + ar, k = k0 + ak;
        As[ak][ar] = A[(((long)(m >> 9) * HH + (k >> 6)) * NSEQ + (m & (NSEQ - 1))) * DK +
                       (k & (DK - 1))];
      }
    } else {
#pragma unroll
      for (int i = 0; i < 4; ++i) {
        const int idx = t + (i << 8);
        const int ar = idx >> 4, ak = idx & 15;
        As[ak][ar] = A[(long)(m0 + ar) * DM + k0 + ak];
      }
    }
#pragma unroll
    for (int i = 0; i < 4; ++i) {
      const int br = (t >> 6) + (i << 2), bc = t & 63;
      Bs[br][bc] = W[(long)(k0 + br) * DM + n0 + bc];
    }
    __syncthreads();
#pragma unroll
    for (int kk = 0; kk < 16; ++kk) {
      const float4 a = *(const float4*)&As[kk][r << 2];
      const float4 bb = *(const float4*)&Bs[kk][c << 2];
      const float av[4] = {a.x, a.y, a.z, a.w};
      const float bw[4] = {bb.x, bb.y, bb.z, bb.w};
#pragma unroll
      for (int i = 0; i < 4; ++i)
#pragma unroll
        for (int j = 0; j < 4; ++j) acc[i][j] += av[i] * bw[j];
    }
    __syncthreads();
  }
  const float4 bv = *(const float4*)&bias[n0 + (c << 2)];
  const float bias4[4] = {bv.x, bv.y, bv.z, bv.w};
  if (mode == 0 || mode == 3) {
    float* Cf = (float*)C;
#pragma unroll
    for (int i = 0; i < 4; ++i) {
      const int m = m0 + (r << 2) + i;
      float4 o;
      o.x = acc[i][0] + bias4[0];
      o.y = acc[i][1] + bias4[1];
      o.z = acc[i][2] + bias4[2];
      o.w = acc[i][3] + bias4[3];
      *(float4*)&Cf[(long)m * DM + n0 + (c << 2)] = o;
    }
  } else if (mode == 1) {
    const int h = n0 >> 6;
    u16* Cu = (u16*)C;
#pragma unroll
    for (int i = 0; i < 4; ++i) {
      const int m = m0 + (r << 2) + i;
      const int bi = m >> 9, n = m & (NSEQ - 1);
      ushort4 o;
      o.x = (u16)f2bf(acc[i][0] + bias4[0]);
      o.y = (u16)f2bf(acc[i][1] + bias4[1]);
      o.z = (u16)f2bf(acc[i][2] + bias4[2]);
      o.w = (u16)f2bf(acc[i][3] + bias4[3]);
      *(ushort4*)&Cu[(((long)bi * HH + h) * NSEQ + n) * DK + (c << 2)] = o;
    }
  } else {
    const int h = n0 >> 6;
    const int bi = m0 >> 9;
    const int seq = (m0 & (NSEQ - 1)) + (r << 2);
    u16* Cu = (u16*)C;
#pragma unroll
    for (int j = 0; j < 4; ++j) {
      const int d = (c << 2) + j;
      ushort4 o;
      o.x = (u16)f2bf(acc[0][j] + bias4[j]);
      o.y = (u16)f2bf(acc[1][j] + bias4[j]);
      o.z = (u16)f2bf(acc[2][j] + bias4[j]);
      o.w = (u16)f2bf(acc[3][j] + bias4[j]);
      *(ushort4*)&Cu[(((long)bi * HH + h) * DK + d) * NSEQ + seq] = o;
    }
  }
}

// ---------------- MFMA dual attention ----------------
// block = (b, h, 64 q-rows); 4 waves x 16 q-rows; no barriers.
// S^T orientation: S^T[k,q] = mfma(A=K[16k x 64d], B=Q^T[64d x 16q]).
// PV: O^T[d,q] = mfma(A=V^T[16d x 32k], B=P^T[32k x 16q]).
// Epilogue: lane holds O^T[d=dt*16+4*l6+r][q=l15], r contiguous in d ->
// direct float4 stores to [b,h,q,64] layout. No epilogue LDS.
__global__ __launch_bounds__(256) void attn_mfma_kernel(
    const u16* __restrict__ q, const u16* __restrict__ k1,
    const u16* __restrict__ k2, const u16* __restrict__ v1t,
    const u16* __restrict__ v2t, const float* __restrict__ aw,
    const u8* __restrict__ mR, const u8* __restrict__ mG,
    float* __restrict__ c1, float* __restrict__ c2) {
  __shared__ __align__(16) u16 eP1[4][16][40];  // [wave][q][32k + pad]
  __shared__ __align__(16) u16 eP2[4][16][40];

  const int t = threadIdx.x;
  const int wid = t >> 6;
  const int lane = t & 63;
  const int l15 = lane & 15;
  const int l6 = lane >> 4;  // 0..3

  const int bid = blockIdx.x;
  const int bh = bid & 127;  // same bh -> same XCD (stride 128 ≡ 0 mod 8)
  const int qt = bid >> 7;
  const int b = bh >> 3, h = bh & 7;
  const int q0 = qt * 64 + wid * 16;

  const long base_k = (long)bh * NSEQ * DK;
  const long base_v = (long)bh * DK * NSEQ;

  // persistent Q^T B-frags: lane holds Q[q0+l15][8*l6+j]
  const long qrow = base_k + (long)(q0 + l15) * DK + 8 * l6;
  const bf16x8 qf0 = *(const bf16x8*)&q[qrow];
  const bf16x8 qf1 = *(const bf16x8*)&q[qrow + 32];

  f32x4 a11[4], a21[4], a22[4], a12[4];
  const f32x4 zero = {0.f, 0.f, 0.f, 0.f};
#pragma unroll
  for (int dt = 0; dt < 4; ++dt) {
    a11[dt] = zero;
    a21[dt] = zero;
    a22[dt] = zero;
    a12[dt] = zero;
  }
  float l1p = 0.f, l2p = 0.f;

  const float* awp = aw + ((long)bh * NSEQ + q0 + l15) * NSEQ;
  const u8* mRp = mR + b * NSEQ;
  const u8* mGp = mG + b * NSEQ;

  for (int kt = 0; kt < NSEQ; kt += 32) {
    // ---- QK^T (both 16-k subtiles, both branches) ----
    const long kr0 = base_k + (long)(kt + l15) * DK + 8 * l6;
    const long kr1 = kr0 + 16 * DK;
    const bf16x8 k1a = *(const bf16x8*)&k1[kr0];
    const bf16x8 k1b = *(const bf16x8*)&k1[kr0 + 32];
    const bf16x8 k1c = *(const bf16x8*)&k1[kr1];
    const bf16x8 k1d = *(const bf16x8*)&k1[kr1 + 32];
    const bf16x8 k2a = *(const bf16x8*)&k2[kr0];
    const bf16x8 k2b = *(const bf16x8*)&k2[kr0 + 32];
    const bf16x8 k2c = *(const bf16x8*)&k2[kr1];
    const bf16x8 k2d = *(const bf16x8*)&k2[kr1 + 32];
    const float4 aw0 = *(const float4*)&awp[kt + 4 * l6];
    const float4 aw1 = *(const float4*)&awp[kt + 16 + 4 * l6];
    const u32 mr0 = *(const u32*)&mRp[kt + 4 * l6];
    const u32 mr1 = *(const u32*)&mRp[kt + 16 + 4 * l6];
    const u32 mg0 = *(const u32*)&mGp[kt + 4 * l6];
    const u32 mg1 = *(const u32*)&mGp[kt + 16 + 4 * l6];

    f32x4 s10 = MFMA16(k1a, qf0, zero);
    s10 = MFMA16(k1b, qf1, s10);
    f32x4 s20 = MFMA16(k2a, qf0, zero);
    s20 = MFMA16(k2b, qf1, s20);
    f32x4 s11 = MFMA16(k1c, qf0, zero);
    s11 = MFMA16(k1d, qf1, s11);
    f32x4 s21 = MFMA16(k2c, qf0, zero);
    s21 = MFMA16(k2d, qf1, s21);

    // ---- scale * aw, mask, exp (rounded to bf16 grid), pack to LDS ----
    const float awa0[4] = {aw0.x, aw0.y, aw0.z, aw0.w};
    const float awa1[4] = {aw1.x, aw1.y, aw1.z, aw1.w};
    float e10[4], e20[4], e11[4], e21[4];
#pragma unroll
    for (int r = 0; r < 4; ++r) {
      const float sa0 = 0.125f * awa0[r];
      const float sa1 = 0.125f * awa1[r];
      e10[r] = ((mr0 >> (8 * r)) & 0xffu) ? 0.f : bfr(__expf(s10[r] * sa0));
      e20[r] = ((mg0 >> (8 * r)) & 0xffu) ? 0.f : bfr(__expf(s20[r] * sa0));
      e11[r] = ((mr1 >> (8 * r)) & 0xffu) ? 0.f : bfr(__expf(s11[r] * sa1));
      e21[r] = ((mg1 >> (8 * r)) & 0xffu) ? 0.f : bfr(__expf(s21[r] * sa1));
      l1p += e10[r] + e11[r];
      l2p += e20[r] + e21[r];
    }
    *(u32*)&eP1[wid][l15][4 * l6] = packbf(e10[0], e10[1]);
    *(u32*)&eP1[wid][l15][4 * l6 + 2] = packbf(e10[2], e10[3]);
    *(u32*)&eP1[wid][l15][16 + 4 * l6] = packbf(e11[0], e11[1]);
    *(u32*)&eP1[wid][l15][16 + 4 * l6 + 2] = packbf(e11[2], e11[3]);
    *(u32*)&eP2[wid][l15][4 * l6] = packbf(e20[0], e20[1]);
    *(u32*)&eP2[wid][l15][4 * l6 + 2] = packbf(e20[2], e20[3]);
    *(u32*)&eP2[wid][l15][16 + 4 * l6] = packbf(e21[0], e21[1]);
    *(u32*)&eP2[wid][l15][16 + 4 * l6 + 2] = packbf(e21[2], e21[3]);

    // ---- P^T B-frags back from LDS (per-wave; same-wave DS is in-order) ----
    const bf16x8 p1 = *(const bf16x8*)&eP1[wid][l15][8 * l6];
    const bf16x8 p2 = *(const bf16x8*)&eP2[wid][l15][8 * l6];

    // ---- PV ----
#pragma unroll
    for (int dt = 0; dt < 4; ++dt) {
      const long vrow = base_v + (long)(dt * 16 + l15) * NSEQ + kt + 8 * l6;
      const bf16x8 vf1 = *(const bf16x8*)&v1t[vrow];
      const bf16x8 vf2 = *(const bf16x8*)&v2t[vrow];
      a11[dt] = MFMA16(vf1, p1, a11[dt]);
      a21[dt] = MFMA16(vf1, p2, a21[dt]);
      a22[dt] = MFMA16(vf2, p2, a22[dt]);
      a12[dt] = MFMA16(vf2, p1, a12[dt]);
    }
  }

  // ---- row sums (lane's q = l15 fixed; partials spread over l6 groups) ----
  float l1 = l1p + __shfl_xor(l1p, 16);
  l1 += __shfl_xor(l1, 32);
  float l2 = l2p + __shfl_xor(l2p, 16);
  l2 += __shfl_xor(l2, 32);
  const float inv1 = 1.f / l1;
  const float inv2 = 1.f / l2;

  // ---- direct stores: c[b,h,q,64]; lane owns d = dt*16 + 4*l6 + (0..3) ----
  const long obase = ((long)bh * NSEQ + q0 + l15) * DK + 4 * l6;
#pragma unroll
  for (int dt = 0; dt < 4; ++dt) {
    float4 o1, o2;
    o1.x = a11[dt][0] * inv1 + 0.1f * a21[dt][0] * inv2;
    o1.y = a11[dt][1] * inv1 + 0.1f * a21[dt][1] * inv2;
    o1.z = a11[dt][2] * inv1 + 0.1f * a21[dt][2] * inv2;
    o1.w = a11[dt][3] * inv1 + 0.1f * a21[dt][3] * inv2;
    o2.x = a22[dt][0] * inv2 + 0.1f * a12[dt][0] * inv1;
    o2.y = a22[dt][1] * inv2 + 0.1f * a12[dt][1] * inv1;
    o2.z = a22[dt][2] * inv2 + 0.1f * a12[dt][2] * inv1;
    o2.w = a22[dt][3] * inv2 + 0.1f * a12[dt][3] * inv1;
    *(float4*)&c1[obase + dt * 16] = o1;
    *(float4*)&c2[obase + dt * 16] = o2;
  }
}

extern "C" void kernel_launch(void* const* d_in, const int* in_sizes, int n_in,
                              void* d_out, int out_size, void* d_ws, size_t ws_size,
                              hipStream_t stream) {
  const float* regions = (const float*)d_in[0];
  const float* grids = (const float*)d_in[1];
  const float* interests = (const float*)d_in[2];
  const void* maskR_raw = d_in[3];
  const void* maskG_raw = d_in[4];
  const float* aw = (const float*)d_in[5];
  const float* Wq = (const float*)d_in[6];
  const float* bq = (const float*)d_in[7];
  const float* Wk = (const float*)d_in[8];
  const float* bk = (const float*)d_in[9];
  const float* Wv = (const float*)d_in[10];
  const float* bvv = (const float*)d_in[11];
  const float* Wo1 = (const float*)d_in[12];
  const float* bo1 = (const float*)d_in[13];
  const float* Wo2 = (const float*)d_in[14];
  const float* bo2 = (const float*)d_in[15];

  const int B = in_sizes[0] / (DM * NSEQ);      // 16
  const long perBF = (long)B * NSEQ * DK * HH;  // u16 elements per projected tensor
  const long perF = (long)B * NSEQ * DM;        // f32 elements per [b,nq,512]

  char* wsb = (char*)d_ws;
  u16* q_bf = (u16*)wsb;  // 8MB each
  u16* k1_bf = q_bf + perBF;
  u16* k2_bf = k1_bf + perBF;
  u16* v1_bf = k2_bf + perBF;
  u16* v2_bf = v1_bf + perBF;
  float* c1_ws = (float*)(v2_bf + perBF);  // 16MB each, layout [b,h,q,64]
  float* c2_ws = c1_ws + perF;
  u8* mR = (u8*)(c2_ws + perF);
  u8* mG = mR + (long)B * NSEQ;

  float* out1 = (float*)d_out;
  float* out2 = out1 + perF;

  const int nMask = B * NSEQ;
  norm_mask_kernel<<<1, 256, 0, stream>>>((const u32*)maskR_raw, mR, nMask);
  norm_mask_kernel<<<1, 256, 0, stream>>>((const u32*)maskG_raw, mG, nMask);

  const int gemmGrid = (B * NSEQ / 64) * (DM / 64);  // 1024
  gemm512_kernel<<<gemmGrid, 256, 0, stream>>>(interests, Wq, bq, q_bf, 1);
  gemm512_kernel<<<gemmGrid, 256, 0, stream>>>(regions, Wk, bk, k1_bf, 1);
  gemm512_kernel<<<gemmGrid, 256, 0, stream>>>(grids, Wk, bk, k2_bf, 1);
  gemm512_kernel<<<gemmGrid, 256, 0, stream>>>(regions, Wv, bvv, v1_bf, 2);
  gemm512_kernel<<<gemmGrid, 256, 0, stream>>>(grids, Wv, bvv, v2_bf, 2);

  attn_mfma_kernel<<<B * HH * (NSEQ / 64), 256, 0, stream>>>(
      q_bf, k1_bf, k2_bf, v1_bf, v2_bf, aw, mR, mG, c1_ws, c2_ws);

  gemm512_kernel<<<gemmGrid, 256, 0, stream>>>(c1_ws, Wo1, bo1, out1, 3);
  gemm512_kernel<<<gemmGrid, 256, 0, stream>>>(c2_ws, Wo2, bo2, out2, 3);
}

// Round 5
// 660.778 us; speedup vs baseline: 3.0835x; 1.2888x over previous
//
#include <hip/hip_runtime.h>
#include <math.h>

#define DM 512
#define HH 8
#define DK 64
#define NSEQ 512

typedef unsigned char u8;
typedef unsigned int u32;
typedef unsigned short u16;
typedef __attribute__((ext_vector_type(8))) short bf16x8;
typedef __attribute__((ext_vector_type(4))) float f32x4;

#define MFMA16(a, b, c) __builtin_amdgcn_mfma_f32_16x16x32_bf16(a, b, c, 0, 0, 0)

__device__ __forceinline__ u32 f2bf(float f) {
  u32 u = __builtin_bit_cast(u32, f);
  return (u + 0x7fffu + ((u >> 16) & 1u)) >> 16;  // RNE
}
__device__ __forceinline__ u32 packbf(float a, float b) {
  return f2bf(a) | (f2bf(b) << 16);
}
__device__ __forceinline__ float bfr(float f) {  // round to bf16 grid
  return __builtin_bit_cast(float, f2bf(f) << 16);
}

// ---------------- mask normalization (dtype-sniffing) ----------------
__global__ __launch_bounds__(256) void norm_mask_kernel(const u32* __restrict__ m,
                                                        u8* __restrict__ o, int nElem) {
  __shared__ int flag;
  if (threadIdx.x == 0) flag = 0;
  __syncthreads();
  const int nw = nElem >> 2;
  int local = 0;
  for (int i = threadIdx.x; i < nw; i += 256)
    if (m[i] > 1u) local = 1;
  if (local) atomicOr(&flag, 1);
  __syncthreads();
  const bool packed = (flag != 0);  // 1-byte bools
  const u8* mb = (const u8*)m;
  for (int i = threadIdx.x; i < nElem; i += 256)
    o[i] = packed ? (mb[i] ? (u8)1 : (u8)0) : (u8)(m[i] != 0u);
}

// ---------------- fp32 -> bf16 row-major convert (3 tensors, 8 elem/thread) --
__global__ __launch_bounds__(256) void cvt_bf16_kernel(
    const float* __restrict__ s0, const float* __restrict__ s1,
    const float* __restrict__ s2, u16* __restrict__ d0, u16* __restrict__ d1,
    u16* __restrict__ d2, const int blocksPer) {
  const int which = blockIdx.x / blocksPer;
  const long pos = ((long)(blockIdx.x % blocksPer) * 256 + threadIdx.x) * 8;
  const float* s = which == 0 ? s0 : (which == 1 ? s1 : s2);
  u16* d = which == 0 ? d0 : (which == 1 ? d1 : d2);
  const float4 f0 = *(const float4*)&s[pos];
  const float4 f1 = *(const float4*)&s[pos + 4];
  uint4 o;
  o.x = packbf(f0.x, f0.y);
  o.y = packbf(f0.z, f0.w);
  o.z = packbf(f1.x, f1.y);
  o.w = packbf(f1.z, f1.w);
  *(uint4*)&d[pos] = o;
}

// ---------------- weight transpose-convert: Wt[n][k] = bf16(W[k][n]) --------
__global__ __launch_bounds__(256) void wtr_kernel(
    const float* __restrict__ w0, const float* __restrict__ w1,
    const float* __restrict__ w2, const float* __restrict__ w3,
    const float* __restrict__ w4, u16* __restrict__ t0, u16* __restrict__ t1,
    u16* __restrict__ t2, u16* __restrict__ t3, u16* __restrict__ t4) {
  __shared__ float ld[32][33];
  const float* src;
  u16* dst;
  switch (blockIdx.y) {
    case 0: src = w0; dst = t0; break;
    case 1: src = w1; dst = t1; break;
    case 2: src = w2; dst = t2; break;
    case 3: src = w3; dst = t3; break;
    default: src = w4; dst = t4; break;
  }
  const int k0 = (blockIdx.x >> 4) << 5;
  const int n0 = (blockIdx.x & 15) << 5;
  const int col = threadIdx.x & 31, row8 = threadIdx.x >> 5;
#pragma unroll
  for (int rr = 0; rr < 4; ++rr) {
    const int kk = row8 + (rr << 3);
    ld[kk][col] = src[(long)(k0 + kk) * DM + n0 + col];
  }
  __syncthreads();
#pragma unroll
  for (int rr = 0; rr < 4; ++rr) {
    const int nn = row8 + (rr << 3);
    dst[(long)(n0 + nn) * DM + k0 + col] = (u16)f2bf(ld[col][nn]);
  }
}

// ---------------- bf16 MFMA GEMM: C[M,512] = A[M,512] @ W[512,512] + bias ----
// Computes C^T = Wt @ A^T per-tile; no LDS, no barriers (compiler pipelines).
// Block: 64m x 64n, 4 waves; wave = 16 n-rows x 64 m (4 mfma frags).
// Lane holds C[m = mtile+l15][n = ntile+4*l6+r], r=0..3 contiguous.
// mode 0: fp32 C row-major. mode 1: bf16 [b,h,seq,64]. mode 2: bf16 [b,h,64,seq].
// a_perm 0: A row-major [m][512]. a_perm 1: A in [b,h,q,64] (m=b*512+q, k=h*64+d).
__global__ __launch_bounds__(256) void mfma_gemm_kernel(
    const u16* __restrict__ A, const u16* __restrict__ Wt,
    const float* __restrict__ bias, void* __restrict__ C, const int mode,
    const int a_perm) {
  const int t = threadIdx.x;
  const int wv = t >> 6;
  const int lane = t & 63;
  const int l15 = lane & 15, l6 = lane >> 4;
  const int bid = blockIdx.x;
  const int m0 = (bid >> 3) << 6;
  const int n0 = (bid & 7) << 6;
  const int ntile = n0 + (wv << 4);

  const u16* wrow = Wt + (long)(ntile + l15) * DM + 8 * l6;

  long abase[4];
#pragma unroll
  for (int mt = 0; mt < 4; ++mt) {
    const int m = m0 + 16 * mt + l15;
    abase[mt] = a_perm ? ((long)(m >> 9) * (HH * NSEQ * DK) + (long)(m & (NSEQ - 1)) * DK)
                       : ((long)m * DM);
  }

  f32x4 acc[4];
  const f32x4 zero = {0.f, 0.f, 0.f, 0.f};
#pragma unroll
  for (int mt = 0; mt < 4; ++mt) acc[mt] = zero;

#pragma unroll 4
  for (int k0 = 0; k0 < DM; k0 += 32) {
    const bf16x8 wf = *(const bf16x8*)&wrow[k0];
    bf16x8 af[4];
    if (a_perm) {
      const long koff = (long)(k0 >> 6) * (NSEQ * DK) + (k0 & 63) + 8 * l6;
#pragma unroll
      for (int mt = 0; mt < 4; ++mt) af[mt] = *(const bf16x8*)&A[abase[mt] + koff];
    } else {
      const int koff = k0 + 8 * l6;
#pragma unroll
      for (int mt = 0; mt < 4; ++mt) af[mt] = *(const bf16x8*)&A[abase[mt] + koff];
    }
#pragma unroll
    for (int mt = 0; mt < 4; ++mt) acc[mt] = MFMA16(wf, af[mt], acc[mt]);
  }

  const float4 bv = *(const float4*)&bias[ntile + 4 * l6];
  const float bb[4] = {bv.x, bv.y, bv.z, bv.w};

  if (mode == 0) {
    float* Cf = (float*)C;
#pragma unroll
    for (int mt = 0; mt < 4; ++mt) {
      const int m = m0 + 16 * mt + l15;
      float4 o;
      o.x = acc[mt][0] + bb[0];
      o.y = acc[mt][1] + bb[1];
      o.z = acc[mt][2] + bb[2];
      o.w = acc[mt][3] + bb[3];
      *(float4*)&Cf[(long)m * DM + ntile + 4 * l6] = o;
    }
  } else if (mode == 1) {
    const int h = n0 >> 6;
    const int d0 = (ntile & 63) + 4 * l6;
    u16* Cu = (u16*)C;
#pragma unroll
    for (int mt = 0; mt < 4; ++mt) {
      const int m = m0 + 16 * mt + l15;
      const int bi = m >> 9, seq = m & (NSEQ - 1);
      ushort4 o;
      o.x = (u16)f2bf(acc[mt][0] + bb[0]);
      o.y = (u16)f2bf(acc[mt][1] + bb[1]);
      o.z = (u16)f2bf(acc[mt][2] + bb[2]);
      o.w = (u16)f2bf(acc[mt][3] + bb[3]);
      *(ushort4*)&Cu[(((long)bi * HH + h) * NSEQ + seq) * DK + d0] = o;
    }
  } else {
    const int h = n0 >> 6;
    const int d0 = (ntile & 63) + 4 * l6;
    u16* Cu = (u16*)C;
#pragma unroll
    for (int mt = 0; mt < 4; ++mt) {
      const int m = m0 + 16 * mt + l15;
      const int bi = m >> 9, seq = m & (NSEQ - 1);
#pragma unroll
      for (int r = 0; r < 4; ++r)
        Cu[(((long)bi * HH + h) * DK + d0 + r) * NSEQ + seq] =
            (u16)f2bf(acc[mt][r] + bb[r]);
    }
  }
}

// ---------------- MFMA dual attention ----------------
// block = (b, h, 64 q-rows); 4 waves x 16 q-rows; no barriers.
// S^T orientation: S^T[k,q] = mfma(A=K[16k x 64d], B=Q^T[64d x 16q]).
// PV: O^T[d,q] = mfma(A=V^T[16d x 32k], B=P^T[32k x 16q]).
// Epilogue: lane holds O^T[d=dt*16+4*l6+r][q=l15], r contiguous in d ->
// direct bf16 ushort4 stores to [b,h,q,64] layout.
__global__ __launch_bounds__(256) void attn_mfma_kernel(
    const u16* __restrict__ q, const u16* __restrict__ k1,
    const u16* __restrict__ k2, const u16* __restrict__ v1t,
    const u16* __restrict__ v2t, const float* __restrict__ aw,
    const u8* __restrict__ mR, const u8* __restrict__ mG,
    u16* __restrict__ c1, u16* __restrict__ c2) {
  __shared__ __align__(16) u16 eP1[4][16][40];  // [wave][q][32k + pad]
  __shared__ __align__(16) u16 eP2[4][16][40];

  const int t = threadIdx.x;
  const int wid = t >> 6;
  const int lane = t & 63;
  const int l15 = lane & 15;
  const int l6 = lane >> 4;  // 0..3

  const int bid = blockIdx.x;
  const int bh = bid & 127;  // same bh -> same XCD (stride 128 ≡ 0 mod 8)
  const int qt = bid >> 7;
  const int b = bh >> 3;
  const int q0 = qt * 64 + wid * 16;

  const long base_k = (long)bh * NSEQ * DK;
  const long base_v = (long)bh * DK * NSEQ;

  // persistent Q^T B-frags: lane holds Q[q0+l15][8*l6+j]
  const long qrow = base_k + (long)(q0 + l15) * DK + 8 * l6;
  const bf16x8 qf0 = *(const bf16x8*)&q[qrow];
  const bf16x8 qf1 = *(const bf16x8*)&q[qrow + 32];

  f32x4 a11[4], a21[4], a22[4], a12[4];
  const f32x4 zero = {0.f, 0.f, 0.f, 0.f};
#pragma unroll
  for (int dt = 0; dt < 4; ++dt) {
    a11[dt] = zero;
    a21[dt] = zero;
    a22[dt] = zero;
    a12[dt] = zero;
  }
  float l1p = 0.f, l2p = 0.f;

  const float* awp = aw + ((long)bh * NSEQ + q0 + l15) * NSEQ;
  const u8* mRp = mR + b * NSEQ;
  const u8* mGp = mG + b * NSEQ;

  for (int kt = 0; kt < NSEQ; kt += 32) {
    // ---- QK^T (both 16-k subtiles, both branches) ----
    const long kr0 = base_k + (long)(kt + l15) * DK + 8 * l6;
    const long kr1 = kr0 + 16 * DK;
    const bf16x8 k1a = *(const bf16x8*)&k1[kr0];
    const bf16x8 k1b = *(const bf16x8*)&k1[kr0 + 32];
    const bf16x8 k1c = *(const bf16x8*)&k1[kr1];
    const bf16x8 k1d = *(const bf16x8*)&k1[kr1 + 32];
    const bf16x8 k2a = *(const bf16x8*)&k2[kr0];
    const bf16x8 k2b = *(const bf16x8*)&k2[kr0 + 32];
    const bf16x8 k2c = *(const bf16x8*)&k2[kr1];
    const bf16x8 k2d = *(const bf16x8*)&k2[kr1 + 32];
    const float4 aw0 = *(const float4*)&awp[kt + 4 * l6];
    const float4 aw1 = *(const float4*)&awp[kt + 16 + 4 * l6];
    const u32 mr0 = *(const u32*)&mRp[kt + 4 * l6];
    const u32 mr1 = *(const u32*)&mRp[kt + 16 + 4 * l6];
    const u32 mg0 = *(const u32*)&mGp[kt + 4 * l6];
    const u32 mg1 = *(const u32*)&mGp[kt + 16 + 4 * l6];

    f32x4 s10 = MFMA16(k1a, qf0, zero);
    s10 = MFMA16(k1b, qf1, s10);
    f32x4 s20 = MFMA16(k2a, qf0, zero);
    s20 = MFMA16(k2b, qf1, s20);
    f32x4 s11 = MFMA16(k1c, qf0, zero);
    s11 = MFMA16(k1d, qf1, s11);
    f32x4 s21 = MFMA16(k2c, qf0, zero);
    s21 = MFMA16(k2d, qf1, s21);

    // ---- scale * aw, mask, exp (rounded to bf16 grid), pack to LDS ----
    const float awa0[4] = {aw0.x, aw0.y, aw0.z, aw0.w};
    const float awa1[4] = {aw1.x, aw1.y, aw1.z, aw1.w};
    float e10[4], e20[4], e11[4], e21[4];
#pragma unroll
    for (int r = 0; r < 4; ++r) {
      const float sa0 = 0.125f * awa0[r];
      const float sa1 = 0.125f * awa1[r];
      e10[r] = ((mr0 >> (8 * r)) & 0xffu) ? 0.f : bfr(__expf(s10[r] * sa0));
      e20[r] = ((mg0 >> (8 * r)) & 0xffu) ? 0.f : bfr(__expf(s20[r] * sa0));
      e11[r] = ((mr1 >> (8 * r)) & 0xffu) ? 0.f : bfr(__expf(s11[r] * sa1));
      e21[r] = ((mg1 >> (8 * r)) & 0xffu) ? 0.f : bfr(__expf(s21[r] * sa1));
      l1p += e10[r] + e11[r];
      l2p += e20[r] + e21[r];
    }
    *(u32*)&eP1[wid][l15][4 * l6] = packbf(e10[0], e10[1]);
    *(u32*)&eP1[wid][l15][4 * l6 + 2] = packbf(e10[2], e10[3]);
    *(u32*)&eP1[wid][l15][16 + 4 * l6] = packbf(e11[0], e11[1]);
    *(u32*)&eP1[wid][l15][16 + 4 * l6 + 2] = packbf(e11[2], e11[3]);
    *(u32*)&eP2[wid][l15][4 * l6] = packbf(e20[0], e20[1]);
    *(u32*)&eP2[wid][l15][4 * l6 + 2] = packbf(e20[2], e20[3]);
    *(u32*)&eP2[wid][l15][16 + 4 * l6] = packbf(e21[0], e21[1]);
    *(u32*)&eP2[wid][l15][16 + 4 * l6 + 2] = packbf(e21[2], e21[3]);

    // ---- P^T B-frags back from LDS (per-wave; same-wave DS is in-order) ----
    const bf16x8 p1 = *(const bf16x8*)&eP1[wid][l15][8 * l6];
    const bf16x8 p2 = *(const bf16x8*)&eP2[wid][l15][8 * l6];

    // ---- PV ----
#pragma unroll
    for (int dt = 0; dt < 4; ++dt) {
      const long vrow = base_v + (long)(dt * 16 + l15) * NSEQ + kt + 8 * l6;
      const bf16x8 vf1 = *(const bf16x8*)&v1t[vrow];
      const bf16x8 vf2 = *(const bf16x8*)&v2t[vrow];
      a11[dt] = MFMA16(vf1, p1, a11[dt]);
      a21[dt] = MFMA16(vf1, p2, a21[dt]);
      a22[dt] = MFMA16(vf2, p2, a22[dt]);
      a12[dt] = MFMA16(vf2, p1, a12[dt]);
    }
  }

  // ---- row sums (lane's q = l15 fixed; partials spread over l6 groups) ----
  float l1 = l1p + __shfl_xor(l1p, 16);
  l1 += __shfl_xor(l1, 32);
  float l2 = l2p + __shfl_xor(l2p, 16);
  l2 += __shfl_xor(l2, 32);
  const float inv1 = 1.f / l1;
  const float inv2 = 1.f / l2;

  // ---- direct bf16 stores: c[b,h,q,64]; lane owns d = dt*16+4*l6+(0..3) ----
  const long obase = ((long)bh * NSEQ + q0 + l15) * DK + 4 * l6;
#pragma unroll
  for (int dt = 0; dt < 4; ++dt) {
    ushort4 s1, s2;
    s1.x = (u16)f2bf(a11[dt][0] * inv1 + 0.1f * a21[dt][0] * inv2);
    s1.y = (u16)f2bf(a11[dt][1] * inv1 + 0.1f * a21[dt][1] * inv2);
    s1.z = (u16)f2bf(a11[dt][2] * inv1 + 0.1f * a21[dt][2] * inv2);
    s1.w = (u16)f2bf(a11[dt][3] * inv1 + 0.1f * a21[dt][3] * inv2);
    s2.x = (u16)f2bf(a22[dt][0] * inv2 + 0.1f * a12[dt][0] * inv1);
    s2.y = (u16)f2bf(a22[dt][1] * inv2 + 0.1f * a12[dt][1] * inv1);
    s2.z = (u16)f2bf(a22[dt][2] * inv2 + 0.1f * a12[dt][2] * inv1);
    s2.w = (u16)f2bf(a22[dt][3] * inv2 + 0.1f * a12[dt][3] * inv1);
    *(ushort4*)&c1[obase + dt * 16] = s1;
    *(ushort4*)&c2[obase + dt * 16] = s2;
  }
}

extern "C" void kernel_launch(void* const* d_in, const int* in_sizes, int n_in,
                              void* d_out, int out_size, void* d_ws, size_t ws_size,
                              hipStream_t stream) {
  const float* regions = (const float*)d_in[0];
  const float* grids = (const float*)d_in[1];
  const float* interests = (const float*)d_in[2];
  const void* maskR_raw = d_in[3];
  const void* maskG_raw = d_in[4];
  const float* aw = (const float*)d_in[5];
  const float* Wq = (const float*)d_in[6];
  const float* bq = (const float*)d_in[7];
  const float* Wk = (const float*)d_in[8];
  const float* bk = (const float*)d_in[9];
  const float* Wv = (const float*)d_in[10];
  const float* bvv = (const float*)d_in[11];
  const float* Wo1 = (const float*)d_in[12];
  const float* bo1 = (const float*)d_in[13];
  const float* Wo2 = (const float*)d_in[14];
  const float* bo2 = (const float*)d_in[15];

  const int B = in_sizes[0] / (DM * NSEQ);      // 16
  const long perBF = (long)B * NSEQ * DM;       // u16 elems per [B,512,512] tensor
  const long wElems = (long)DM * DM;            // 512x512

  u16* p = (u16*)d_ws;
  u16* ibf = p; p += perBF;   // bf16 activations
  u16* rbf = p; p += perBF;
  u16* gbf = p; p += perBF;
  u16* wtq = p; p += wElems;  // bf16 transposed weights
  u16* wtk = p; p += wElems;
  u16* wtv = p; p += wElems;
  u16* wto1 = p; p += wElems;
  u16* wto2 = p; p += wElems;
  u16* q_bf = p; p += perBF;  // projections
  u16* k1_bf = p; p += perBF;
  u16* k2_bf = p; p += perBF;
  u16* v1_bf = p; p += perBF;
  u16* v2_bf = p; p += perBF;
  u16* c1_bf = p; p += perBF;  // attention outputs [b,h,q,64] bf16
  u16* c2_bf = p; p += perBF;
  u8* mR = (u8*)p;
  u8* mG = mR + (long)B * NSEQ;

  float* out1 = (float*)d_out;
  float* out2 = out1 + perBF;

  const int nMask = B * NSEQ;
  norm_mask_kernel<<<1, 256, 0, stream>>>((const u32*)maskR_raw, mR, nMask);
  norm_mask_kernel<<<1, 256, 0, stream>>>((const u32*)maskG_raw, mG, nMask);

  const int cvtBlocksPer = (int)(perBF / (256 * 8));  // 2048
  cvt_bf16_kernel<<<3 * cvtBlocksPer, 256, 0, stream>>>(interests, regions, grids,
                                                        ibf, rbf, gbf, cvtBlocksPer);
  wtr_kernel<<<dim3(256, 5), 256, 0, stream>>>(Wq, Wk, Wv, Wo1, Wo2, wtq, wtk,
                                               wtv, wto1, wto2);

  const int gemmGrid = (B * NSEQ / 64) * (DM / 64);  // 1024
  mfma_gemm_kernel<<<gemmGrid, 256, 0, stream>>>(ibf, wtq, bq, q_bf, 1, 0);
  mfma_gemm_kernel<<<gemmGrid, 256, 0, stream>>>(rbf, wtk, bk, k1_bf, 1, 0);
  mfma_gemm_kernel<<<gemmGrid, 256, 0, stream>>>(gbf, wtk, bk, k2_bf, 1, 0);
  mfma_gemm_kernel<<<gemmGrid, 256, 0, stream>>>(rbf, wtv, bvv, v1_bf, 2, 0);
  mfma_gemm_kernel<<<gemmGrid, 256, 0, stream>>>(gbf, wtv, bvv, v2_bf, 2, 0);

  attn_mfma_kernel<<<B * HH * (NSEQ / 64), 256, 0, stream>>>(
      q_bf, k1_bf, k2_bf, v1_bf, v2_bf, aw, mR, mG, c1_bf, c2_bf);

  mfma_gemm_kernel<<<gemmGrid, 256, 0, stream>>>(c1_bf, wto1, bo1, out1, 0, 1);
  mfma_gemm_kernel<<<gemmGrid, 256, 0, stream>>>(c2_bf, wto2, bo2, out2, 0, 1);
}

// Round 6
// 470.737 us; speedup vs baseline: 4.3284x; 1.4037x over previous
//
#include <hip/hip_runtime.h>
#include <math.h>

#define DM 512
#define HH 8
#define DK 64
#define NSEQ 512

typedef unsigned char u8;
typedef unsigned int u32;
typedef unsigned short u16;
typedef __attribute__((ext_vector_type(8))) short bf16x8;
typedef __attribute__((ext_vector_type(4))) float f32x4;

#define MFMA16(a, b, c) __builtin_amdgcn_mfma_f32_16x16x32_bf16(a, b, c, 0, 0, 0)

__device__ __forceinline__ u32 f2bf(float f) {
  u32 u = __builtin_bit_cast(u32, f);
  return (u + 0x7fffu + ((u >> 16) & 1u)) >> 16;  // RNE
}
__device__ __forceinline__ u32 packbf(float a, float b) {
  return f2bf(a) | (f2bf(b) << 16);
}
__device__ __forceinline__ float bfr(float f) {  // round to bf16 grid
  return __builtin_bit_cast(float, f2bf(f) << 16);
}
__device__ __forceinline__ void gload16(const u16* g, void* l) {
  __builtin_amdgcn_global_load_lds(
      (const __attribute__((address_space(1))) void*)g,
      (__attribute__((address_space(3))) void*)l, 16, 0, 0);
}

// ---------------- mask normalization (dtype-sniffing) ----------------
__global__ __launch_bounds__(256) void norm_mask_kernel(const u32* __restrict__ m,
                                                        u8* __restrict__ o, int nElem) {
  __shared__ int flag;
  if (threadIdx.x == 0) flag = 0;
  __syncthreads();
  const int nw = nElem >> 2;
  int local = 0;
  for (int i = threadIdx.x; i < nw; i += 256)
    if (m[i] > 1u) local = 1;
  if (local) atomicOr(&flag, 1);
  __syncthreads();
  const bool packed = (flag != 0);  // 1-byte bools
  const u8* mb = (const u8*)m;
  for (int i = threadIdx.x; i < nElem; i += 256)
    o[i] = packed ? (mb[i] ? (u8)1 : (u8)0) : (u8)(m[i] != 0u);
}

// ---------------- fp32 -> bf16 row-major convert (3 tensors, 8 elem/thread) --
__global__ __launch_bounds__(256) void cvt_bf16_kernel(
    const float* __restrict__ s0, const float* __restrict__ s1,
    const float* __restrict__ s2, u16* __restrict__ d0, u16* __restrict__ d1,
    u16* __restrict__ d2, const int blocksPer) {
  const int which = blockIdx.x / blocksPer;
  const long pos = ((long)(blockIdx.x % blocksPer) * 256 + threadIdx.x) * 8;
  const float* s = which == 0 ? s0 : (which == 1 ? s1 : s2);
  u16* d = which == 0 ? d0 : (which == 1 ? d1 : d2);
  const float4 f0 = *(const float4*)&s[pos];
  const float4 f1 = *(const float4*)&s[pos + 4];
  uint4 o;
  o.x = packbf(f0.x, f0.y);
  o.y = packbf(f0.z, f0.w);
  o.z = packbf(f1.x, f1.y);
  o.w = packbf(f1.z, f1.w);
  *(uint4*)&d[pos] = o;
}

// ---------------- weight transpose-convert: Wt[n][k] = bf16(W[k][n]) --------
__global__ __launch_bounds__(256) void wtr_kernel(
    const float* __restrict__ w0, const float* __restrict__ w1,
    const float* __restrict__ w2, const float* __restrict__ w3,
    const float* __restrict__ w4, u16* __restrict__ t0, u16* __restrict__ t1,
    u16* __restrict__ t2, u16* __restrict__ t3, u16* __restrict__ t4) {
  __shared__ float ld[32][33];
  const float* src;
  u16* dst;
  switch (blockIdx.y) {
    case 0: src = w0; dst = t0; break;
    case 1: src = w1; dst = t1; break;
    case 2: src = w2; dst = t2; break;
    case 3: src = w3; dst = t3; break;
    default: src = w4; dst = t4; break;
  }
  const int k0 = (blockIdx.x >> 4) << 5;
  const int n0 = (blockIdx.x & 15) << 5;
  const int col = threadIdx.x & 31, row8 = threadIdx.x >> 5;
#pragma unroll
  for (int rr = 0; rr < 4; ++rr) {
    const int kk = row8 + (rr << 3);
    ld[kk][col] = src[(long)(k0 + kk) * DM + n0 + col];
  }
  __syncthreads();
#pragma unroll
  for (int rr = 0; rr < 4; ++rr) {
    const int nn = row8 + (rr << 3);
    dst[(long)(n0 + nn) * DM + k0 + col] = (u16)f2bf(ld[col][nn]);
  }
}

// ---------------- LDS-staged bf16 MFMA GEMM ----------------
// C[M,512] = A[M,512] @ W[512,512] + bias, computed as D[n,m] = Wt rows x A^T.
// BM=128, BN=64, BK=64; 4 waves (wave = 64m x 32n = 4x2 frags of 16x16).
// global_load_lds width 16, linear LDS dest; XOR swizzle (octet ^= row&7)
// applied on the global SOURCE address and on the ds_read side (rule 21).
// Rows are 128 B = 32 banks -> swizzled ds_read_b128 is <=2-way (free).
// mode 0: fp32 C row-major. mode 1: bf16 [b,h,seq,64]. mode 2: bf16 [b,h,64,seq].
// a_perm 0: A row-major [m][512]. a_perm 1: A in [b,h,q,64].
__global__ __launch_bounds__(256) void mfma_gemm_kernel(
    const u16* __restrict__ A, const u16* __restrict__ Wt,
    const float* __restrict__ bias, void* __restrict__ C, const int mode,
    const int a_perm) {
  __shared__ __align__(16) u16 smA[128 * 64];  // 16 KB
  __shared__ __align__(16) u16 smB[64 * 64];   // 8 KB

  const int t = threadIdx.x;
  const int wid = t >> 6, lane = t & 63;
  const int l15 = lane & 15, l6 = lane >> 4;

  // bijective XCD swizzle (512 blocks, 8 XCDs, 64 blocks each)
  const int bid = (blockIdx.x & 7) * 64 + (blockIdx.x >> 3);
  const int m0 = (bid >> 3) * 128;
  const int n0 = (bid & 7) * 64;

  const int wm = (wid >> 1) * 64;  // 0 / 64
  const int wn = (wid & 1) * 32;   // 0 / 32

  f32x4 acc[4][2];
  const f32x4 zero = {0.f, 0.f, 0.f, 0.f};
#pragma unroll
  for (int mt = 0; mt < 4; ++mt)
#pragma unroll
    for (int nt = 0; nt < 2; ++nt) acc[mt][nt] = zero;

  for (int kt = 0; kt < DM; kt += 64) {
    __syncthreads();  // previous iter's reads done before overwrite
    // ---- stage A: 1024 chunks of 16B; chunk c -> row c>>3, slot c&7 ----
#pragma unroll
    for (int j = 0; j < 4; ++j) {
      const int c = j * 256 + t;
      const int row = c >> 3, s = c & 7;
      const int o = s ^ (row & 7);  // inverse-swizzled source octet
      const int m = m0 + row;
      long gofs;
      if (a_perm)
        gofs = (((long)(m >> 9) * HH + (kt >> 6)) * NSEQ + (m & (NSEQ - 1))) * DK + o * 8;
      else
        gofs = (long)m * DM + kt + o * 8;
      gload16(A + gofs, (char*)smA + c * 16);
    }
    // ---- stage B (Wt): 512 chunks ----
#pragma unroll
    for (int j = 0; j < 2; ++j) {
      const int c = j * 256 + t;
      const int row = c >> 3, s = c & 7;
      const int o = s ^ (row & 7);
      gload16(Wt + (long)(n0 + row) * DM + kt + o * 8, (char*)smB + c * 16);
    }
    __syncthreads();  // implicit vmcnt(0) drain before barrier

    // ---- compute: 2 k-halves of 32 ----
#pragma unroll
    for (int kh = 0; kh < 2; ++kh) {
      bf16x8 bfrag[2], afrag[4];
#pragma unroll
      for (int nt = 0; nt < 2; ++nt) {
        const int R = wn + nt * 16 + l15;
        const int o = (kh * 4 + l6) ^ (R & 7);
        bfrag[nt] = *(const bf16x8*)&smB[R * 64 + o * 8];
      }
#pragma unroll
      for (int mt = 0; mt < 4; ++mt) {
        const int R = wm + mt * 16 + l15;
        const int o = (kh * 4 + l6) ^ (R & 7);
        afrag[mt] = *(const bf16x8*)&smA[R * 64 + o * 8];
      }
#pragma unroll
      for (int mt = 0; mt < 4; ++mt)
#pragma unroll
        for (int nt = 0; nt < 2; ++nt)
          acc[mt][nt] = MFMA16(bfrag[nt], afrag[mt], acc[mt][nt]);
    }
  }

  // ---- epilogue: lane holds D[n = wn+nt*16+4*l6+r][m = wm+mt*16+l15] ----
  if (mode == 0) {
    float* Cf = (float*)C;
#pragma unroll
    for (int mt = 0; mt < 4; ++mt) {
      const int m = m0 + wm + mt * 16 + l15;
#pragma unroll
      for (int nt = 0; nt < 2; ++nt) {
        const int n = n0 + wn + nt * 16 + 4 * l6;
        const float4 bv = *(const float4*)&bias[n];
        float4 o;
        o.x = acc[mt][nt][0] + bv.x;
        o.y = acc[mt][nt][1] + bv.y;
        o.z = acc[mt][nt][2] + bv.z;
        o.w = acc[mt][nt][3] + bv.w;
        *(float4*)&Cf[(long)m * DM + n] = o;
      }
    }
  } else if (mode == 1) {
    const int h = n0 >> 6;  // BN=64 -> uniform per block
    u16* Cu = (u16*)C;
#pragma unroll
    for (int mt = 0; mt < 4; ++mt) {
      const int m = m0 + wm + mt * 16 + l15;
      const int bi = m >> 9, seq = m & (NSEQ - 1);
#pragma unroll
      for (int nt = 0; nt < 2; ++nt) {
        const int d = wn + nt * 16 + 4 * l6;
        const float4 bv = *(const float4*)&bias[n0 + d];
        ushort4 o;
        o.x = (u16)f2bf(acc[mt][nt][0] + bv.x);
        o.y = (u16)f2bf(acc[mt][nt][1] + bv.y);
        o.z = (u16)f2bf(acc[mt][nt][2] + bv.z);
        o.w = (u16)f2bf(acc[mt][nt][3] + bv.w);
        *(ushort4*)&Cu[(((long)bi * HH + h) * NSEQ + seq) * DK + d] = o;
      }
    }
  } else {
    const int h = n0 >> 6;
    u16* Cu = (u16*)C;
#pragma unroll
    for (int mt = 0; mt < 4; ++mt) {
      const int m = m0 + wm + mt * 16 + l15;
      const int bi = m >> 9, seq = m & (NSEQ - 1);
#pragma unroll
      for (int nt = 0; nt < 2; ++nt) {
        const int d = wn + nt * 16 + 4 * l6;
        const float4 bv = *(const float4*)&bias[n0 + d];
        const float bb[4] = {bv.x, bv.y, bv.z, bv.w};
#pragma unroll
        for (int r = 0; r < 4; ++r)
          Cu[(((long)bi * HH + h) * DK + d + r) * NSEQ + seq] =
              (u16)f2bf(acc[mt][nt][r] + bb[r]);
      }
    }
  }
}

// ---------------- MFMA dual attention (unchanged from round 4) ----------------
__global__ __launch_bounds__(256) void attn_mfma_kernel(
    const u16* __restrict__ q, const u16* __restrict__ k1,
    const u16* __restrict__ k2, const u16* __restrict__ v1t,
    const u16* __restrict__ v2t, const float* __restrict__ aw,
    const u8* __restrict__ mR, const u8* __restrict__ mG,
    u16* __restrict__ c1, u16* __restrict__ c2) {
  __shared__ __align__(16) u16 eP1[4][16][40];  // [wave][q][32k + pad]
  __shared__ __align__(16) u16 eP2[4][16][40];

  const int t = threadIdx.x;
  const int wid = t >> 6;
  const int lane = t & 63;
  const int l15 = lane & 15;
  const int l6 = lane >> 4;  // 0..3

  const int bid = blockIdx.x;
  const int bh = bid & 127;  // same bh -> same XCD (stride 128 ≡ 0 mod 8)
  const int qt = bid >> 7;
  const int b = bh >> 3;
  const int q0 = qt * 64 + wid * 16;

  const long base_k = (long)bh * NSEQ * DK;
  const long base_v = (long)bh * DK * NSEQ;

  const long qrow = base_k + (long)(q0 + l15) * DK + 8 * l6;
  const bf16x8 qf0 = *(const bf16x8*)&q[qrow];
  const bf16x8 qf1 = *(const bf16x8*)&q[qrow + 32];

  f32x4 a11[4], a21[4], a22[4], a12[4];
  const f32x4 zero = {0.f, 0.f, 0.f, 0.f};
#pragma unroll
  for (int dt = 0; dt < 4; ++dt) {
    a11[dt] = zero;
    a21[dt] = zero;
    a22[dt] = zero;
    a12[dt] = zero;
  }
  float l1p = 0.f, l2p = 0.f;

  const float* awp = aw + ((long)bh * NSEQ + q0 + l15) * NSEQ;
  const u8* mRp = mR + b * NSEQ;
  const u8* mGp = mG + b * NSEQ;

  for (int kt = 0; kt < NSEQ; kt += 32) {
    const long kr0 = base_k + (long)(kt + l15) * DK + 8 * l6;
    const long kr1 = kr0 + 16 * DK;
    const bf16x8 k1a = *(const bf16x8*)&k1[kr0];
    const bf16x8 k1b = *(const bf16x8*)&k1[kr0 + 32];
    const bf16x8 k1c = *(const bf16x8*)&k1[kr1];
    const bf16x8 k1d = *(const bf16x8*)&k1[kr1 + 32];
    const bf16x8 k2a = *(const bf16x8*)&k2[kr0];
    const bf16x8 k2b = *(const bf16x8*)&k2[kr0 + 32];
    const bf16x8 k2c = *(const bf16x8*)&k2[kr1];
    const bf16x8 k2d = *(const bf16x8*)&k2[kr1 + 32];
    const float4 aw0 = *(const float4*)&awp[kt + 4 * l6];
    const float4 aw1 = *(const float4*)&awp[kt + 16 + 4 * l6];
    const u32 mr0 = *(const u32*)&mRp[kt + 4 * l6];
    const u32 mr1 = *(const u32*)&mRp[kt + 16 + 4 * l6];
    const u32 mg0 = *(const u32*)&mGp[kt + 4 * l6];
    const u32 mg1 = *(const u32*)&mGp[kt + 16 + 4 * l6];

    f32x4 s10 = MFMA16(k1a, qf0, zero);
    s10 = MFMA16(k1b, qf1, s10);
    f32x4 s20 = MFMA16(k2a, qf0, zero);
    s20 = MFMA16(k2b, qf1, s20);
    f32x4 s11 = MFMA16(k1c, qf0, zero);
    s11 = MFMA16(k1d, qf1, s11);
    f32x4 s21 = MFMA16(k2c, qf0, zero);
    s21 = MFMA16(k2d, qf1, s21);

    const float awa0[4] = {aw0.x, aw0.y, aw0.z, aw0.w};
    const float awa1[4] = {aw1.x, aw1.y, aw1.z, aw1.w};
    float e10[4], e20[4], e11[4], e21[4];
#pragma unroll
    for (int r = 0; r < 4; ++r) {
      const float sa0 = 0.125f * awa0[r];
      const float sa1 = 0.125f * awa1[r];
      e10[r] = ((mr0 >> (8 * r)) & 0xffu) ? 0.f : bfr(__expf(s10[r] * sa0));
      e20[r] = ((mg0 >> (8 * r)) & 0xffu) ? 0.f : bfr(__expf(s20[r] * sa0));
      e11[r] = ((mr1 >> (8 * r)) & 0xffu) ? 0.f : bfr(__expf(s11[r] * sa1));
      e21[r] = ((mg1 >> (8 * r)) & 0xffu) ? 0.f : bfr(__expf(s21[r] * sa1));
      l1p += e10[r] + e11[r];
      l2p += e20[r] + e21[r];
    }
    *(u32*)&eP1[wid][l15][4 * l6] = packbf(e10[0], e10[1]);
    *(u32*)&eP1[wid][l15][4 * l6 + 2] = packbf(e10[2], e10[3]);
    *(u32*)&eP1[wid][l15][16 + 4 * l6] = packbf(e11[0], e11[1]);
    *(u32*)&eP1[wid][l15][16 + 4 * l6 + 2] = packbf(e11[2], e11[3]);
    *(u32*)&eP2[wid][l15][4 * l6] = packbf(e20[0], e20[1]);
    *(u32*)&eP2[wid][l15][4 * l6 + 2] = packbf(e20[2], e20[3]);
    *(u32*)&eP2[wid][l15][16 + 4 * l6] = packbf(e21[0], e21[1]);
    *(u32*)&eP2[wid][l15][16 + 4 * l6 + 2] = packbf(e21[2], e21[3]);

    const bf16x8 p1 = *(const bf16x8*)&eP1[wid][l15][8 * l6];
    const bf16x8 p2 = *(const bf16x8*)&eP2[wid][l15][8 * l6];

#pragma unroll
    for (int dt = 0; dt < 4; ++dt) {
      const long vrow = base_v + (long)(dt * 16 + l15) * NSEQ + kt + 8 * l6;
      const bf16x8 vf1 = *(const bf16x8*)&v1t[vrow];
      const bf16x8 vf2 = *(const bf16x8*)&v2t[vrow];
      a11[dt] = MFMA16(vf1, p1, a11[dt]);
      a21[dt] = MFMA16(vf1, p2, a21[dt]);
      a22[dt] = MFMA16(vf2, p2, a22[dt]);
      a12[dt] = MFMA16(vf2, p1, a12[dt]);
    }
  }

  float l1 = l1p + __shfl_xor(l1p, 16);
  l1 += __shfl_xor(l1, 32);
  float l2 = l2p + __shfl_xor(l2p, 16);
  l2 += __shfl_xor(l2, 32);
  const float inv1 = 1.f / l1;
  const float inv2 = 1.f / l2;

  const long obase = ((long)bh * NSEQ + q0 + l15) * DK + 4 * l6;
#pragma unroll
  for (int dt = 0; dt < 4; ++dt) {
    ushort4 s1, s2;
    s1.x = (u16)f2bf(a11[dt][0] * inv1 + 0.1f * a21[dt][0] * inv2);
    s1.y = (u16)f2bf(a11[dt][1] * inv1 + 0.1f * a21[dt][1] * inv2);
    s1.z = (u16)f2bf(a11[dt][2] * inv1 + 0.1f * a21[dt][2] * inv2);
    s1.w = (u16)f2bf(a11[dt][3] * inv1 + 0.1f * a21[dt][3] * inv2);
    s2.x = (u16)f2bf(a22[dt][0] * inv2 + 0.1f * a12[dt][0] * inv1);
    s2.y = (u16)f2bf(a22[dt][1] * inv2 + 0.1f * a12[dt][1] * inv1);
    s2.z = (u16)f2bf(a22[dt][2] * inv2 + 0.1f * a12[dt][2] * inv1);
    s2.w = (u16)f2bf(a22[dt][3] * inv2 + 0.1f * a12[dt][3] * inv1);
    *(ushort4*)&c1[obase + dt * 16] = s1;
    *(ushort4*)&c2[obase + dt * 16] = s2;
  }
}

extern "C" void kernel_launch(void* const* d_in, const int* in_sizes, int n_in,
                              void* d_out, int out_size, void* d_ws, size_t ws_size,
                              hipStream_t stream) {
  const float* regions = (const float*)d_in[0];
  const float* grids = (const float*)d_in[1];
  const float* interests = (const float*)d_in[2];
  const void* maskR_raw = d_in[3];
  const void* maskG_raw = d_in[4];
  const float* aw = (const float*)d_in[5];
  const float* Wq = (const float*)d_in[6];
  const float* bq = (const float*)d_in[7];
  const float* Wk = (const float*)d_in[8];
  const float* bk = (const float*)d_in[9];
  const float* Wv = (const float*)d_in[10];
  const float* bvv = (const float*)d_in[11];
  const float* Wo1 = (const float*)d_in[12];
  const float* bo1 = (const float*)d_in[13];
  const float* Wo2 = (const float*)d_in[14];
  const float* bo2 = (const float*)d_in[15];

  const int B = in_sizes[0] / (DM * NSEQ);  // 16
  const long perBF = (long)B * NSEQ * DM;   // u16 elems per [B,512,512] tensor
  const long wElems = (long)DM * DM;        // 512x512

  u16* p = (u16*)d_ws;
  u16* ibf = p; p += perBF;   // bf16 activations
  u16* rbf = p; p += perBF;
  u16* gbf = p; p += perBF;
  u16* wtq = p; p += wElems;  // bf16 transposed weights
  u16* wtk = p; p += wElems;
  u16* wtv = p; p += wElems;
  u16* wto1 = p; p += wElems;
  u16* wto2 = p; p += wElems;
  u16* q_bf = p; p += perBF;  // projections
  u16* k1_bf = p; p += perBF;
  u16* k2_bf = p; p += perBF;
  u16* v1_bf = p; p += perBF;
  u16* v2_bf = p; p += perBF;
  u16* c1_bf = p; p += perBF;  // attention outputs [b,h,q,64] bf16
  u16* c2_bf = p; p += perBF;
  u8* mR = (u8*)p;
  u8* mG = mR + (long)B * NSEQ;

  float* out1 = (float*)d_out;
  float* out2 = out1 + perBF;

  const int nMask = B * NSEQ;
  norm_mask_kernel<<<1, 256, 0, stream>>>((const u32*)maskR_raw, mR, nMask);
  norm_mask_kernel<<<1, 256, 0, stream>>>((const u32*)maskG_raw, mG, nMask);

  const int cvtBlocksPer = (int)(perBF / (256 * 8));  // 2048
  cvt_bf16_kernel<<<3 * cvtBlocksPer, 256, 0, stream>>>(interests, regions, grids,
                                                        ibf, rbf, gbf, cvtBlocksPer);
  wtr_kernel<<<dim3(256, 5), 256, 0, stream>>>(Wq, Wk, Wv, Wo1, Wo2, wtq, wtk,
                                               wtv, wto1, wto2);

  const int gemmGrid = (B * NSEQ / 128) * (DM / 64);  // 512
  mfma_gemm_kernel<<<gemmGrid, 256, 0, stream>>>(ibf, wtq, bq, q_bf, 1, 0);
  mfma_gemm_kernel<<<gemmGrid, 256, 0, stream>>>(rbf, wtk, bk, k1_bf, 1, 0);
  mfma_gemm_kernel<<<gemmGrid, 256, 0, stream>>>(gbf, wtk, bk, k2_bf, 1, 0);
  mfma_gemm_kernel<<<gemmGrid, 256, 0, stream>>>(rbf, wtv, bvv, v1_bf, 2, 0);
  mfma_gemm_kernel<<<gemmGrid, 256, 0, stream>>>(gbf, wtv, bvv, v2_bf, 2, 0);

  attn_mfma_kernel<<<B * HH * (NSEQ / 64), 256, 0, stream>>>(
      q_bf, k1_bf, k2_bf, v1_bf, v2_bf, aw, mR, mG, c1_bf, c2_bf);

  mfma_gemm_kernel<<<gemmGrid, 256, 0, stream>>>(c1_bf, wto1, bo1, out1, 0, 1);
  mfma_gemm_kernel<<<gemmGrid, 256, 0, stream>>>(c2_bf, wto2, bo2, out2, 0, 1);
}